// Round 13
// baseline (35.128 us; speedup 1.0000x reference)
//
#include <hip/hip_runtime.h>
#include <hip/hip_bf16.h>

typedef int   v4i __attribute__((ext_vector_type(4)));
typedef float v4f __attribute__((ext_vector_type(4)));

#define HWSZ 3136   // 56*56
#define IMW  56
#define PADW 58     // 56+2 halo
#define PHW  3364   // 58*58
#define CIN  64
#define COUT 128

__device__ __forceinline__ float step_size(float a) {
    a = a > 0.f ? a : 0.f;              // relu(alpha)
    return 2.0f * a / 254.0f;
}

__device__ __forceinline__ int quant1(float x, float s) {
    float v = rintf(x / s);             // round-half-even like jnp.round
    v = fminf(127.f, fmaxf(-127.f, v)); // clip(-127, 127)
    return (int)v;
}

__device__ __forceinline__ unsigned int pack4(int a, int b, int c, int d) {
    return (unsigned int)(a & 255) | ((unsigned int)(b & 255) << 8) |
           ((unsigned int)(c & 255) << 16) | ((unsigned int)(d & 255) << 24);
}

__device__ __forceinline__ void gload_lds16(const signed char* g, signed char* l) {
    __builtin_amdgcn_global_load_lds(
        (const __attribute__((address_space(1))) void*)g,
        (__attribute__((address_space(3))) void*)l, 16, 0, 0);
}

// ---------------- fused quantize (UNCHANGED from R12) ----------------
__global__ __launch_bounds__(256) void quant_kernel(const float* __restrict__ x,
                                                    const float* __restrict__ w,
                                                    const float* __restrict__ alpha_x,
                                                    const float* __restrict__ alpha_w,
                                                    signed char* __restrict__ cx,
                                                    signed char* __restrict__ wt) {
    int t = threadIdx.x;
    int b = blockIdx.x;
    if (b >= 392) {
        if (b >= 680) {
            int q = (b - 680) * 256 + t;
            int n = q / 912;
            int r = q % 912;
            int px = r >> 2, seg = r & 3;
            int ph, pw;
            if (px < 58)       { ph = 0;  pw = px; }
            else if (px < 116) { ph = 57; pw = px - 58; }
            else { int k = px - 116; ph = 1 + (k >> 1); pw = (k & 1) * 57; }
            v4i z = {0, 0, 0, 0};
            *(v4i*)(cx + ((size_t)n * PHW + ph * PADW + pw) * 64 + seg * 16) = z;
            return;
        }
        float s = step_size(alpha_w[0]);
        int j = (b - 392) * 256 + t;   // wt flat index in [tap][o][c], 73728 total
        int tap = j / 8192;
        int r   = j % 8192;
        int o   = r >> 6;
        int c   = r & 63;
        float v = w[((size_t)o * 64 + c) * 9 + tap];
        wt[j] = (signed char)quant1(v, s);
        return;
    }

    __shared__ unsigned int tile32[64 * 17];
    float s = step_size(alpha_x[0]);
    int nb  = b / 49;
    int hw0 = (b % 49) * 64;
    int g   = t & 15;
    int cq  = t >> 4;
    int p   = t >> 2;
    int seg = t & 3;
    int hw  = hw0 + p;
    int h   = hw / IMW, wq = hw % IMW;
    signed char* cxp = cx + ((size_t)(h + 1) * PADW + (wq + 1)) * 64 + seg * 16;

#pragma unroll
    for (int i = 0; i < 4; ++i) {
        int n = nb * 4 + i;
        const float* xb = x + ((size_t)n * CIN + cq * 4) * HWSZ + hw0 + g * 4;
        v4f f0 = *(const v4f*)(xb);
        v4f f1 = *(const v4f*)(xb + HWSZ);
        v4f f2 = *(const v4f*)(xb + 2 * HWSZ);
        v4f f3 = *(const v4f*)(xb + 3 * HWSZ);
        if (i) __syncthreads();
#pragma unroll
        for (int j = 0; j < 4; ++j) {
            unsigned int u = pack4(quant1(f0[j], s), quant1(f1[j], s),
                                   quant1(f2[j], s), quant1(f3[j], s));
            tile32[(g * 4 + j) * 17 + cq] = u;
        }
        __syncthreads();
        int base = p * 17 + seg * 4;
        v4i val;
        val[0] = (int)tile32[base + 0];
        val[1] = (int)tile32[base + 1];
        val[2] = (int)tile32[base + 2];
        val[3] = (int)tile32[base + 3];
        *(v4i*)(cxp + (size_t)n * PHW * 64) = val;
    }
}

// ---- stage one 64-px tile's A window (5 padded rows) into an LDS buffer ----
__device__ __forceinline__ void stage_tile(const signed char* __restrict__ cx,
                                           int tile, signed char* buf,
                                           int wid, int lane) {
    int p0  = tile * 64;
    int n   = p0 / HWSZ;
    int hw0 = p0 % HWSZ;
    int h0  = hw0 / IMW;
    int us  = h0 - 1; if (us > 52) us = 52;
    const signed char* src = cx + ((size_t)n * PHW + (size_t)(us + 1) * PADW) * 64;
#pragma unroll
    for (int r = 0; r < 10; ++r) {
        int slot = r * 128 + wid * 64;   // wave-uniform base
        gload_lds16(src + (size_t)(slot + lane) * 16, buf + slot * 16);
    }
}

// ---- compute one tile from LDS buffer and store ----
__device__ __forceinline__ void compute_store(const signed char* buf,
                                              const v4i (&breg)[9][4],
                                              float scale, int tile,
                                              int obase, int row, int kg,
                                              float* __restrict__ out) {
    int p0  = tile * 64;
    int n   = p0 / HWSZ;
    int hw0 = p0 % HWSZ;
    int h0  = hw0 / IMW;
    int us  = h0 - 1; if (us > 52) us = 52;
    int lbase[4];
#pragma unroll
    for (int pt = 0; pt < 4; ++pt) {
        int hwp = hw0 + pt * 16 + row;
        int hh  = hwp / IMW, ww = hwp % IMW;
        lbase[pt] = ((hh - us) * PADW + (ww + 1)) * 64 + kg * 16;
    }
    v4i acc[4][4] = {};
#pragma unroll
    for (int tap = 0; tap < 9; ++tap) {
        int doff = ((tap / 3 - 1) * PADW + (tap % 3 - 1)) * 64;
        v4i a[4];
#pragma unroll
        for (int pt = 0; pt < 4; ++pt)
            a[pt] = *(const v4i*)(buf + lbase[pt] + doff);
#pragma unroll
        for (int pt = 0; pt < 4; ++pt)
#pragma unroll
            for (int ot = 0; ot < 4; ++ot)
                acc[pt][ot] = __builtin_amdgcn_mfma_i32_16x16x64_i8(a[pt], breg[tap][ot], acc[pt][ot], 0, 0, 0);
    }
#pragma unroll
    for (int pt = 0; pt < 4; ++pt) {
        int hw = hw0 + pt * 16 + kg * 4;
#pragma unroll
        for (int ot = 0; ot < 4; ++ot) {
            int o = obase + ot * 16 + row;
            v4f v;
            v[0] = scale * (float)acc[pt][ot][0];
            v[1] = scale * (float)acc[pt][ot][1];
            v[2] = scale * (float)acc[pt][ot][2];
            v[3] = scale * (float)acc[pt][ot][3];
            *(v4f*)(out + ((size_t)n * COUT + o) * HWSZ + hw) = v;
        }
    }
}

// ---------------- persistent 2-tile conv: A dbuf in LDS, B in regs ----------------
// block = 128 thr = 2 waves (o halves); block owns tiles {2s, 2s+1} (64 px each)
// grid = 784 (784%8==0, XCD swizzle). B loaded once per block (amortized 2x).
// Tile1's A staged during tile0's compute; tile0's stores overlap tile1's compute
// via counted s_waitcnt vmcnt(16) (waits the 10 stage loads, not the 16 stores).
__global__ __launch_bounds__(128, 1) void conv_kernel(const signed char* __restrict__ cx,
                                                      const signed char* __restrict__ wt,
                                                      const float* __restrict__ ax,
                                                      const float* __restrict__ aw,
                                                      float* __restrict__ out) {
    __shared__ signed char as_[2][20480];
    float scale = step_size(ax[0]) * step_size(aw[0]);
    int tid  = threadIdx.x;
    int lane = tid & 63;
    int wid  = tid >> 6;    // 0..1: o half
    int row  = lane & 15;
    int kg   = lane >> 4;

    int bid = blockIdx.x;
    int swz = (bid & 7) * 98 + (bid >> 3);   // contiguous 98-block chunk per XCD
    int t0  = swz * 2;
    int obase = wid * 64;

    // stage tile0, preload B (all under one vmcnt(0) drain)
    stage_tile(cx, t0, as_[0], wid, lane);
    const signed char* wb = wt + (obase + row) * 64 + kg * 16;
    v4i breg[9][4];
#pragma unroll
    for (int tap = 0; tap < 9; ++tap)
#pragma unroll
        for (int ot = 0; ot < 4; ++ot)
            breg[tap][ot] = *(const v4i*)(wb + tap * (COUT * 64) + ot * (16 * 64));

    asm volatile("s_waitcnt vmcnt(0)" ::: "memory");
    __syncthreads();
    // pin B so the scheduler can't sink the loads into the loops
#pragma unroll
    for (int tap = 0; tap < 9; ++tap)
#pragma unroll
        for (int ot = 0; ot < 4; ++ot)
            asm volatile("" :: "v"(breg[tap][ot]));

    // stage tile1 while tile0 computes
    stage_tile(cx, t0 + 1, as_[1], wid, lane);
    compute_store(as_[0], breg, scale, t0, obase, row, kg, out);

    // wait only the 10 stage loads (16 stores may remain in flight)
    asm volatile("s_waitcnt vmcnt(16)" ::: "memory");
    __builtin_amdgcn_s_barrier();
    __builtin_amdgcn_sched_barrier(0);

    compute_store(as_[1], breg, scale, t0 + 1, obase, row, kg, out);
}

extern "C" void kernel_launch(void* const* d_in, const int* in_sizes, int n_in,
                              void* d_out, int out_size, void* d_ws, size_t ws_size,
                              hipStream_t stream) {
    const float* x  = (const float*)d_in[0];
    const float* w  = (const float*)d_in[1];
    const float* ax = (const float*)d_in[2];
    const float* aw = (const float*)d_in[3];
    float* out = (float*)d_out;

    signed char* cx = (signed char*)d_ws;   // 32*3364*64 = 6,889,472 B (padded NHWC)
    signed char* wt = cx + 6889472;         // 9*128*64   =    73,728 B  [tap][o][c]

    quant_kernel<<<794, 256, 0, stream>>>(x, w, ax, aw, cx, wt);
    conv_kernel<<<784, 128, 0, stream>>>(cx, wt, ax, aw, out);
}